// Round 1
// baseline (652.988 us; speedup 1.0000x reference)
//
#include <hip/hip_runtime.h>
#include <hip/hip_bf16.h>

#define NNODES 50000
#define NEDGES 640000
#define NGRAPH 64
#define HD     128

// ---------------------------------------------------------------------------
// CSR build: histogram -> 2-level exclusive scan -> scatter
// ---------------------------------------------------------------------------
__global__ __launch_bounds__(256) void hist_k(const int* __restrict__ dst,
                                              int* __restrict__ count, int E) {
    int e = blockIdx.x * 256 + threadIdx.x;
    if (e < E) atomicAdd(&count[dst[e]], 1);
}

__global__ __launch_bounds__(256) void scan1_k(const int* __restrict__ count,
                                               int* __restrict__ row_tmp,
                                               int* __restrict__ blocksum, int N) {
    __shared__ int s[256];
    int t = threadIdx.x;
    int i = blockIdx.x * 256 + t;
    int v = (i < N) ? count[i] : 0;
    s[t] = v;
    __syncthreads();
    for (int off = 1; off < 256; off <<= 1) {
        int nv = s[t];
        if (t >= off) nv += s[t - off];
        __syncthreads();
        s[t] = nv;
        __syncthreads();
    }
    if (i < N) row_tmp[i] = s[t];          // inclusive scan within block
    if (t == 255) blocksum[blockIdx.x] = s[255];
}

__global__ __launch_bounds__(256) void scan2_k(const int* __restrict__ blocksum,
                                               int* __restrict__ blockoff, int nB) {
    __shared__ int s[256];
    int t = threadIdx.x;
    int v = (t < nB) ? blocksum[t] : 0;
    s[t] = v;
    __syncthreads();
    for (int off = 1; off < 256; off <<= 1) {
        int nv = s[t];
        if (t >= off) nv += s[t - off];
        __syncthreads();
        s[t] = nv;
        __syncthreads();
    }
    if (t < nB) blockoff[t] = s[t] - v;    // exclusive
}

__global__ __launch_bounds__(256) void scan3_k(const int* __restrict__ count,
                                               const int* __restrict__ row_tmp,
                                               const int* __restrict__ blockoff,
                                               int* __restrict__ row_start,
                                               int* __restrict__ cur, int N, int E) {
    int i = blockIdx.x * 256 + threadIdx.x;
    if (i < N) {
        int excl = row_tmp[i] - count[i] + blockoff[i >> 8];
        row_start[i] = excl;
        cur[i] = excl;
    }
    if (i == N) row_start[N] = E;
}

__global__ __launch_bounds__(256) void scatter_k(const int* __restrict__ src,
                                                 const int* __restrict__ dst,
                                                 int* __restrict__ cur,
                                                 int* __restrict__ nbr, int E) {
    int e = blockIdx.x * 256 + threadIdx.x;
    if (e < E) {
        int d = dst[e];
        int pos = atomicAdd(&cur[d], 1);
        nbr[pos] = src[e];
    }
}

// graph start offsets via binary search on sorted batch
__global__ void gstart_k(const int* __restrict__ batch, int* __restrict__ gstart, int N) {
    int g = blockIdx.x * blockDim.x + threadIdx.x;
    if (g <= NGRAPH) {
        int lo = 0, hi = N;
        while (lo < hi) {
            int mid = (lo + hi) >> 1;
            if (batch[mid] < g) lo = mid + 1; else hi = mid;
        }
        gstart[g] = lo;
    }
}

// ---------------------------------------------------------------------------
// Layer 1: t = relu((x + agg(x)) @ W1 + b1)   with x: N x 8, W1: 8 x 128
// ---------------------------------------------------------------------------
__global__ __launch_bounds__(256) void lin8_k(const float* __restrict__ x,
                                              const int* __restrict__ row_start,
                                              const int* __restrict__ nbr,
                                              const float* __restrict__ W,   // 8 x 128
                                              const float* __restrict__ bias,
                                              float* __restrict__ out, int nNodes) {
    __shared__ float hin[128][8];
    int t = threadIdx.x;
    int n0 = blockIdx.x * 128;
    {
        int r = t >> 1;
        int half = t & 1;
        int n = n0 + r;
        float4 v = make_float4(0.f, 0.f, 0.f, 0.f);
        if (n < nNodes) {
            v = *(const float4*)(x + (size_t)n * 8 + half * 4);
            int rs = row_start[n], re = row_start[n + 1];
            for (int p = rs; p < re; ++p) {
                int s = nbr[p];
                float4 u = *(const float4*)(x + (size_t)s * 8 + half * 4);
                v.x += u.x; v.y += u.y; v.z += u.z; v.w += u.w;
            }
        }
        *(float4*)(&hin[r][half * 4]) = v;
    }
    __syncthreads();
    int tx = t & 15, ty = t >> 4;
    // preload W columns tx*8..tx*8+7 for all 8 k into registers
    float w[8][8];
#pragma unroll
    for (int k = 0; k < 8; ++k) {
        float4 w0 = *(const float4*)(W + k * HD + tx * 8);
        float4 w1 = *(const float4*)(W + k * HD + tx * 8 + 4);
        w[k][0] = w0.x; w[k][1] = w0.y; w[k][2] = w0.z; w[k][3] = w0.w;
        w[k][4] = w1.x; w[k][5] = w1.y; w[k][6] = w1.z; w[k][7] = w1.w;
    }
    float4 b0 = *(const float4*)(bias + tx * 8);
    float4 b1v = *(const float4*)(bias + tx * 8 + 4);
    float bb[8] = {b0.x, b0.y, b0.z, b0.w, b1v.x, b1v.y, b1v.z, b1v.w};
#pragma unroll
    for (int i = 0; i < 8; ++i) {
        int r = ty * 8 + i;
        int n = n0 + r;
        if (n >= nNodes) continue;
        float a[8];
        float4 a0 = *(const float4*)(&hin[r][0]);
        float4 a1 = *(const float4*)(&hin[r][4]);
        a[0] = a0.x; a[1] = a0.y; a[2] = a0.z; a[3] = a0.w;
        a[4] = a1.x; a[5] = a1.y; a[6] = a1.z; a[7] = a1.w;
        float o[8];
#pragma unroll
        for (int jj = 0; jj < 8; ++jj) {
            float acc = bb[jj];
#pragma unroll
            for (int k = 0; k < 8; ++k) acc += a[k] * w[k][jj];
            o[jj] = fmaxf(acc, 0.f);
        }
        float4 o0 = make_float4(o[0], o[1], o[2], o[3]);
        float4 o1 = make_float4(o[4], o[5], o[6], o[7]);
        *(float4*)(out + (size_t)n * HD + tx * 8) = o0;
        *(float4*)(out + (size_t)n * HD + tx * 8 + 4) = o1;
    }
}

// ---------------------------------------------------------------------------
// Main GEMM: out = relu(A_in @ W + b), A_in optionally = h + CSR-aggregated h
// Tile: 128 nodes x 128 cols per block, 256 threads, A staged in LDS
// (xor-swizzled k-groups -> conflict-free compute reads)
// ---------------------------------------------------------------------------
template <bool AGGR>
__global__ __launch_bounds__(256) void mm128_k(const float* __restrict__ Ain,
                                               const int* __restrict__ row_start,
                                               const int* __restrict__ nbr,
                                               const float* __restrict__ W,    // 128x128
                                               const float* __restrict__ bias, // 128
                                               float* __restrict__ out,
                                               int nNodes) {
    __shared__ float4 As4[128 * 32];   // 64 KB, [row][kgroup] with xor swizzle
    int t = threadIdx.x;
    int n0 = blockIdx.x * 128;
    // ---- staging: row r handled by one 32-lane half-wave (fused gather-sum) ----
    for (int i = 0; i < 16; ++i) {
        int idx = i * 256 + t;
        int r = idx >> 5;
        int cg = idx & 31;
        int n = n0 + r;
        float4 v = make_float4(0.f, 0.f, 0.f, 0.f);
        if (n < nNodes) {
            v = *(const float4*)(Ain + (size_t)n * HD + cg * 4);
            if (AGGR) {
                int rs = row_start[n], re = row_start[n + 1];
                for (int p = rs; p < re; ++p) {
                    int s = nbr[p];
                    float4 u = *(const float4*)(Ain + (size_t)s * HD + cg * 4);
                    v.x += u.x; v.y += u.y; v.z += u.z; v.w += u.w;
                }
            }
        }
        As4[r * 32 + (cg ^ ((r >> 3) & 7))] = v;
    }
    __syncthreads();
    // ---- compute: thread = (ty: 8 nodes, tx: 8 cols) ----
    int tx = t & 15, ty = t >> 4;
    float acc[8][8];
#pragma unroll
    for (int i = 0; i < 8; ++i)
#pragma unroll
        for (int j = 0; j < 8; ++j) acc[i][j] = 0.f;
    const int sw = ty & 7;
    for (int kg = 0; kg < 32; ++kg) {
        float4 av[8];
#pragma unroll
        for (int i = 0; i < 8; ++i) av[i] = As4[(ty * 8 + i) * 32 + (kg ^ sw)];
#pragma unroll
        for (int q = 0; q < 4; ++q) {
            int k = kg * 4 + q;
            float4 w0 = *(const float4*)(W + k * HD + tx * 8);
            float4 w1 = *(const float4*)(W + k * HD + tx * 8 + 4);
#pragma unroll
            for (int i = 0; i < 8; ++i) {
                float a = (q == 0) ? av[i].x : (q == 1) ? av[i].y : (q == 2) ? av[i].z : av[i].w;
                acc[i][0] += a * w0.x; acc[i][1] += a * w0.y;
                acc[i][2] += a * w0.z; acc[i][3] += a * w0.w;
                acc[i][4] += a * w1.x; acc[i][5] += a * w1.y;
                acc[i][6] += a * w1.z; acc[i][7] += a * w1.w;
            }
        }
    }
    // ---- epilogue: bias + relu + store ----
    float4 b0 = *(const float4*)(bias + tx * 8);
    float4 b1v = *(const float4*)(bias + tx * 8 + 4);
#pragma unroll
    for (int i = 0; i < 8; ++i) {
        int n = n0 + ty * 8 + i;
        if (n >= nNodes) continue;
        float4 o0, o1;
        o0.x = fmaxf(acc[i][0] + b0.x, 0.f);
        o0.y = fmaxf(acc[i][1] + b0.y, 0.f);
        o0.z = fmaxf(acc[i][2] + b0.z, 0.f);
        o0.w = fmaxf(acc[i][3] + b0.w, 0.f);
        o1.x = fmaxf(acc[i][4] + b1v.x, 0.f);
        o1.y = fmaxf(acc[i][5] + b1v.y, 0.f);
        o1.z = fmaxf(acc[i][6] + b1v.z, 0.f);
        o1.w = fmaxf(acc[i][7] + b1v.w, 0.f);
        *(float4*)(out + (size_t)n * HD + tx * 8) = o0;
        *(float4*)(out + (size_t)n * HD + tx * 8 + 4) = o1;
    }
}

// ---------------------------------------------------------------------------
// Pooling: pooled[g][coloff + j] += sum over nodes of graph g of h[n][j]
// grid (64 graphs, 8 parts), 128 threads = feature j
// ---------------------------------------------------------------------------
__global__ __launch_bounds__(128) void pool_k(const float* __restrict__ h,
                                              const int* __restrict__ gstart,
                                              float* __restrict__ pooled, int coloff) {
    int g = blockIdx.x, part = blockIdx.y, t = threadIdx.x;
    int lo = gstart[g], hi = gstart[g + 1];
    int cnt = hi - lo;
    if (cnt <= 0) return;
    int chunk = (cnt + 7) >> 3;
    int s = lo + part * chunk;
    int e = s + chunk; if (e > hi) e = hi;
    float acc = 0.f;
    for (int n = s; n < e; ++n) acc += h[(size_t)n * HD + t];
    if (s < e) atomicAdd(&pooled[g * 384 + coloff + t], acc);
}

// ---------------------------------------------------------------------------
// Classifier: z = relu(bn(pooled @ W1 + b1)); out = z @ W2 + b2
// one block per graph, 256 threads = output feature j
// ---------------------------------------------------------------------------
__global__ __launch_bounds__(256) void cls_k(const float* __restrict__ pooled,
                                             const float* __restrict__ W1,  // 384x256
                                             const float* __restrict__ b1,
                                             const float* __restrict__ gamma,
                                             const float* __restrict__ beta,
                                             const float* __restrict__ mean,
                                             const float* __restrict__ var,
                                             const float* __restrict__ W2,  // 256x4
                                             const float* __restrict__ b2,
                                             float* __restrict__ out) {
    __shared__ float pg[384];
    __shared__ float z[256];
    int g = blockIdx.x, j = threadIdx.x;
    pg[j] = pooled[g * 384 + j];
    if (j < 128) pg[256 + j] = pooled[g * 384 + 256 + j];
    __syncthreads();
    float acc = b1[j];
    for (int k = 0; k < 384; ++k) acc += pg[k] * W1[k * 256 + j];
    acc = (acc - mean[j]) * rsqrtf(var[j] + 1e-5f) * gamma[j] + beta[j];
    z[j] = fmaxf(acc, 0.f);
    __syncthreads();
    if (j < 4) {
        float o = b2[j];
        for (int k = 0; k < 256; ++k) o += z[k] * W2[k * 4 + j];
        out[g * 4 + j] = o;
    }
}

// ---------------------------------------------------------------------------
extern "C" void kernel_launch(void* const* d_in, const int* in_sizes, int n_in,
                              void* d_out, int out_size, void* d_ws, size_t ws_size,
                              hipStream_t stream) {
    const int N = NNODES, E = NEDGES;
    const float* x     = (const float*)d_in[0];
    const int*   ei    = (const int*)d_in[1];
    const int*   batch = (const int*)d_in[2];
    const float* l1W1 = (const float*)d_in[3];
    const float* l1b1 = (const float*)d_in[4];
    const float* l1W2 = (const float*)d_in[5];
    const float* l1b2 = (const float*)d_in[6];
    const float* l2W1 = (const float*)d_in[7];
    const float* l2b1 = (const float*)d_in[8];
    const float* l2W2 = (const float*)d_in[9];
    const float* l2b2 = (const float*)d_in[10];
    const float* l3W1 = (const float*)d_in[11];
    const float* l3b1 = (const float*)d_in[12];
    const float* l3W2 = (const float*)d_in[13];
    const float* l3b2 = (const float*)d_in[14];
    const float* cW1  = (const float*)d_in[15];
    const float* cb1  = (const float*)d_in[16];
    const float* bnG  = (const float*)d_in[17];
    const float* bnB  = (const float*)d_in[18];
    const float* bnM  = (const float*)d_in[19];
    const float* bnV  = (const float*)d_in[20];
    const float* cW2  = (const float*)d_in[21];
    const float* cb2  = (const float*)d_in[22];

    const int* src = ei;
    const int* dst = ei + E;

    // workspace layout (floats)
    float* ws   = (float*)d_ws;
    float* tmp  = ws;                         // N*128
    float* h1   = tmp + (size_t)N * HD;       // N*128
    float* h2   = h1 + (size_t)N * HD;        // N*128
    float* h3   = h2 + (size_t)N * HD;        // N*128
    float* pooled = h3 + (size_t)N * HD;      // 64*384
    int* count    = (int*)(pooled + 64 * 384);  // N
    int* row_tmp  = count + N;                  // N
    int* blocksum = row_tmp + N;                // 256
    int* blockoff = blocksum + 256;             // 256
    int* row_start = blockoff + 256;            // N+1
    int* cur       = row_start + N + 1;         // N
    int* nbr       = cur + N;                   // E
    int* gstart    = nbr + E;                   // 65

    hipMemsetAsync(count, 0, (size_t)N * 4, stream);
    hipMemsetAsync(pooled, 0, (size_t)64 * 384 * 4, stream);

    const int nB = (N + 255) / 256;      // 196 blocks of 256
    hist_k<<<(E + 255) / 256, 256, 0, stream>>>(dst, count, E);
    scan1_k<<<nB, 256, 0, stream>>>(count, row_tmp, blocksum, N);
    scan2_k<<<1, 256, 0, stream>>>(blocksum, blockoff, nB);
    scan3_k<<<nB, 256, 0, stream>>>(count, row_tmp, blockoff, row_start, cur, N, E);
    scatter_k<<<(E + 255) / 256, 256, 0, stream>>>(src, dst, cur, nbr, E);
    gstart_k<<<1, 128, 0, stream>>>(batch, gstart, N);

    const int mb = (N + 127) / 128;      // 391 tiles
    // layer 1
    lin8_k<<<mb, 256, 0, stream>>>(x, row_start, nbr, l1W1, l1b1, tmp, N);
    mm128_k<false><<<mb, 256, 0, stream>>>(tmp, nullptr, nullptr, l1W2, l1b2, h1, N);
    pool_k<<<dim3(NGRAPH, 8), 128, 0, stream>>>(h1, gstart, pooled, 0);
    // layer 2
    mm128_k<true><<<mb, 256, 0, stream>>>(h1, row_start, nbr, l2W1, l2b1, tmp, N);
    mm128_k<false><<<mb, 256, 0, stream>>>(tmp, nullptr, nullptr, l2W2, l2b2, h2, N);
    pool_k<<<dim3(NGRAPH, 8), 128, 0, stream>>>(h2, gstart, pooled, 128);
    // layer 3
    mm128_k<true><<<mb, 256, 0, stream>>>(h2, row_start, nbr, l3W1, l3b1, tmp, N);
    mm128_k<false><<<mb, 256, 0, stream>>>(tmp, nullptr, nullptr, l3W2, l3b2, h3, N);
    pool_k<<<dim3(NGRAPH, 8), 128, 0, stream>>>(h3, gstart, pooled, 256);
    // classifier
    cls_k<<<NGRAPH, 256, 0, stream>>>(pooled, cW1, cb1, bnG, bnB, bnM, bnV, cW2, cb2,
                                      (float*)d_out);
}

// Round 2
// 468.776 us; speedup vs baseline: 1.3930x; 1.3930x over previous
//
#include <hip/hip_runtime.h>
#include <hip/hip_bf16.h>

#define NNODES 50000
#define NEDGES 640000
#define NGRAPH 64
#define HD     128

// ---------------------------------------------------------------------------
// CSR build: histogram -> 2-level exclusive scan -> scatter
// ---------------------------------------------------------------------------
__global__ __launch_bounds__(256) void hist_k(const int* __restrict__ dst,
                                              int* __restrict__ count, int E) {
    int e = blockIdx.x * 256 + threadIdx.x;
    if (e < E) atomicAdd(&count[dst[e]], 1);
}

__global__ __launch_bounds__(256) void scan1_k(const int* __restrict__ count,
                                               int* __restrict__ row_tmp,
                                               int* __restrict__ blocksum, int N) {
    __shared__ int s[256];
    int t = threadIdx.x;
    int i = blockIdx.x * 256 + t;
    int v = (i < N) ? count[i] : 0;
    s[t] = v;
    __syncthreads();
    for (int off = 1; off < 256; off <<= 1) {
        int nv = s[t];
        if (t >= off) nv += s[t - off];
        __syncthreads();
        s[t] = nv;
        __syncthreads();
    }
    if (i < N) row_tmp[i] = s[t];          // inclusive scan within block
    if (t == 255) blocksum[blockIdx.x] = s[255];
}

__global__ __launch_bounds__(256) void scan2_k(const int* __restrict__ blocksum,
                                               int* __restrict__ blockoff, int nB) {
    __shared__ int s[256];
    int t = threadIdx.x;
    int v = (t < nB) ? blocksum[t] : 0;
    s[t] = v;
    __syncthreads();
    for (int off = 1; off < 256; off <<= 1) {
        int nv = s[t];
        if (t >= off) nv += s[t - off];
        __syncthreads();
        s[t] = nv;
        __syncthreads();
    }
    if (t < nB) blockoff[t] = s[t] - v;    // exclusive
}

__global__ __launch_bounds__(256) void scan3_k(const int* __restrict__ count,
                                               const int* __restrict__ row_tmp,
                                               const int* __restrict__ blockoff,
                                               int* __restrict__ row_start,
                                               int* __restrict__ cur, int N, int E) {
    int i = blockIdx.x * 256 + threadIdx.x;
    if (i < N) {
        int excl = row_tmp[i] - count[i] + blockoff[i >> 8];
        row_start[i] = excl;
        cur[i] = excl;
    }
    if (i == N) row_start[N] = E;
}

__global__ __launch_bounds__(256) void scatter_k(const int* __restrict__ src,
                                                 const int* __restrict__ dst,
                                                 int* __restrict__ cur,
                                                 int* __restrict__ nbr, int E) {
    int e = blockIdx.x * 256 + threadIdx.x;
    if (e < E) {
        int d = dst[e];
        int pos = atomicAdd(&cur[d], 1);
        nbr[pos] = src[e];
    }
}

// graph start offsets via binary search on sorted batch
__global__ void gstart_k(const int* __restrict__ batch, int* __restrict__ gstart, int N) {
    int g = blockIdx.x * blockDim.x + threadIdx.x;
    if (g <= NGRAPH) {
        int lo = 0, hi = N;
        while (lo < hi) {
            int mid = (lo + hi) >> 1;
            if (batch[mid] < g) lo = mid + 1; else hi = mid;
        }
        gstart[g] = lo;
    }
}

// ---------------------------------------------------------------------------
// Standalone aggregation for 128-wide h: out[n] = h[n] + sum_{s in nbr(n)} h[s]
// One WAVE per node: lane holds float2 (128 floats = 64 lanes x 2).
// Wave-uniform CSR walk, neighbor loop unrolled x4 for memory-level parallelism.
// Zero LDS, low VGPR -> max occupancy; this is the latency-hiding fix.
// ---------------------------------------------------------------------------
__global__ __launch_bounds__(256) void agg128_k(const float* __restrict__ h,
                                                const int* __restrict__ row_start,
                                                const int* __restrict__ nbr,
                                                float* __restrict__ out, int nNodes) {
    int wid = (blockIdx.x * 256 + threadIdx.x) >> 6;   // node index
    int lane = threadIdx.x & 63;
    if (wid >= nNodes) return;
    size_t col = (size_t)lane * 2;
    float2 acc = *(const float2*)(h + (size_t)wid * HD + col);
    int rs = row_start[wid], re = row_start[wid + 1];
    int p = rs;
    for (; p + 4 <= re; p += 4) {
        int s0 = nbr[p], s1 = nbr[p + 1], s2 = nbr[p + 2], s3 = nbr[p + 3];
        float2 u0 = *(const float2*)(h + (size_t)s0 * HD + col);
        float2 u1 = *(const float2*)(h + (size_t)s1 * HD + col);
        float2 u2 = *(const float2*)(h + (size_t)s2 * HD + col);
        float2 u3 = *(const float2*)(h + (size_t)s3 * HD + col);
        acc.x += u0.x + u1.x + u2.x + u3.x;
        acc.y += u0.y + u1.y + u2.y + u3.y;
    }
    for (; p < re; ++p) {
        int s = nbr[p];
        float2 u = *(const float2*)(h + (size_t)s * HD + col);
        acc.x += u.x;
        acc.y += u.y;
    }
    *(float2*)(out + (size_t)wid * HD + col) = acc;
}

// ---------------------------------------------------------------------------
// Layer 1: t = relu((x + agg(x)) @ W1 + b1)   with x: N x 8, W1: 8 x 128
// ---------------------------------------------------------------------------
__global__ __launch_bounds__(256) void lin8_k(const float* __restrict__ x,
                                              const int* __restrict__ row_start,
                                              const int* __restrict__ nbr,
                                              const float* __restrict__ W,   // 8 x 128
                                              const float* __restrict__ bias,
                                              float* __restrict__ out, int nNodes) {
    __shared__ float hin[128][8];
    int t = threadIdx.x;
    int n0 = blockIdx.x * 128;
    {
        int r = t >> 1;
        int half = t & 1;
        int n = n0 + r;
        float4 v = make_float4(0.f, 0.f, 0.f, 0.f);
        if (n < nNodes) {
            v = *(const float4*)(x + (size_t)n * 8 + half * 4);
            int rs = row_start[n], re = row_start[n + 1];
            int p = rs;
            for (; p + 4 <= re; p += 4) {
                int s0 = nbr[p], s1 = nbr[p + 1], s2 = nbr[p + 2], s3 = nbr[p + 3];
                float4 u0 = *(const float4*)(x + (size_t)s0 * 8 + half * 4);
                float4 u1 = *(const float4*)(x + (size_t)s1 * 8 + half * 4);
                float4 u2 = *(const float4*)(x + (size_t)s2 * 8 + half * 4);
                float4 u3 = *(const float4*)(x + (size_t)s3 * 8 + half * 4);
                v.x += u0.x + u1.x + u2.x + u3.x;
                v.y += u0.y + u1.y + u2.y + u3.y;
                v.z += u0.z + u1.z + u2.z + u3.z;
                v.w += u0.w + u1.w + u2.w + u3.w;
            }
            for (; p < re; ++p) {
                int s = nbr[p];
                float4 u = *(const float4*)(x + (size_t)s * 8 + half * 4);
                v.x += u.x; v.y += u.y; v.z += u.z; v.w += u.w;
            }
        }
        *(float4*)(&hin[r][half * 4]) = v;
    }
    __syncthreads();
    int tx = t & 15, ty = t >> 4;
    // preload W columns tx*8..tx*8+7 for all 8 k into registers
    float w[8][8];
#pragma unroll
    for (int k = 0; k < 8; ++k) {
        float4 w0 = *(const float4*)(W + k * HD + tx * 8);
        float4 w1 = *(const float4*)(W + k * HD + tx * 8 + 4);
        w[k][0] = w0.x; w[k][1] = w0.y; w[k][2] = w0.z; w[k][3] = w0.w;
        w[k][4] = w1.x; w[k][5] = w1.y; w[k][6] = w1.z; w[k][7] = w1.w;
    }
    float4 b0 = *(const float4*)(bias + tx * 8);
    float4 b1v = *(const float4*)(bias + tx * 8 + 4);
    float bb[8] = {b0.x, b0.y, b0.z, b0.w, b1v.x, b1v.y, b1v.z, b1v.w};
#pragma unroll
    for (int i = 0; i < 8; ++i) {
        int r = ty * 8 + i;
        int n = n0 + r;
        if (n >= nNodes) continue;
        float a[8];
        float4 a0 = *(const float4*)(&hin[r][0]);
        float4 a1 = *(const float4*)(&hin[r][4]);
        a[0] = a0.x; a[1] = a0.y; a[2] = a0.z; a[3] = a0.w;
        a[4] = a1.x; a[5] = a1.y; a[6] = a1.z; a[7] = a1.w;
        float o[8];
#pragma unroll
        for (int jj = 0; jj < 8; ++jj) {
            float acc = bb[jj];
#pragma unroll
            for (int k = 0; k < 8; ++k) acc += a[k] * w[k][jj];
            o[jj] = fmaxf(acc, 0.f);
        }
        float4 o0 = make_float4(o[0], o[1], o[2], o[3]);
        float4 o1 = make_float4(o[4], o[5], o[6], o[7]);
        *(float4*)(out + (size_t)n * HD + tx * 8) = o0;
        *(float4*)(out + (size_t)n * HD + tx * 8 + 4) = o1;
    }
}

// ---------------------------------------------------------------------------
// Main GEMM: out = relu(A_in @ W + b). Pure streaming (no gather).
// Tile: 128 nodes x 128 cols per block, 256 threads, A staged in LDS
// (xor-swizzled k-groups -> conflict-free compute reads).
// In-place safe: block reads all its rows to LDS before writing any output.
// ---------------------------------------------------------------------------
__global__ __launch_bounds__(256) void mm128_k(const float* __restrict__ Ain,
                                               const float* __restrict__ W,    // 128x128
                                               const float* __restrict__ bias, // 128
                                               float* __restrict__ out,
                                               int nNodes) {
    __shared__ float4 As4[128 * 32];   // 64 KB, [row][kgroup] with xor swizzle
    int t = threadIdx.x;
    int n0 = blockIdx.x * 128;
    // ---- staging ----
    for (int i = 0; i < 16; ++i) {
        int idx = i * 256 + t;
        int r = idx >> 5;
        int cg = idx & 31;
        int n = n0 + r;
        float4 v = make_float4(0.f, 0.f, 0.f, 0.f);
        if (n < nNodes) v = *(const float4*)(Ain + (size_t)n * HD + cg * 4);
        As4[r * 32 + (cg ^ ((r >> 3) & 7))] = v;
    }
    __syncthreads();
    // ---- compute: thread = (ty: 8 nodes, tx: 8 cols) ----
    int tx = t & 15, ty = t >> 4;
    float acc[8][8];
#pragma unroll
    for (int i = 0; i < 8; ++i)
#pragma unroll
        for (int j = 0; j < 8; ++j) acc[i][j] = 0.f;
    const int sw = ty & 7;
    for (int kg = 0; kg < 32; ++kg) {
        float4 av[8];
#pragma unroll
        for (int i = 0; i < 8; ++i) av[i] = As4[(ty * 8 + i) * 32 + (kg ^ sw)];
#pragma unroll
        for (int q = 0; q < 4; ++q) {
            int k = kg * 4 + q;
            float4 w0 = *(const float4*)(W + k * HD + tx * 8);
            float4 w1 = *(const float4*)(W + k * HD + tx * 8 + 4);
#pragma unroll
            for (int i = 0; i < 8; ++i) {
                float a = (q == 0) ? av[i].x : (q == 1) ? av[i].y : (q == 2) ? av[i].z : av[i].w;
                acc[i][0] += a * w0.x; acc[i][1] += a * w0.y;
                acc[i][2] += a * w0.z; acc[i][3] += a * w0.w;
                acc[i][4] += a * w1.x; acc[i][5] += a * w1.y;
                acc[i][6] += a * w1.z; acc[i][7] += a * w1.w;
            }
        }
    }
    // ---- epilogue: bias + relu + store ----
    float4 b0 = *(const float4*)(bias + tx * 8);
    float4 b1v = *(const float4*)(bias + tx * 8 + 4);
#pragma unroll
    for (int i = 0; i < 8; ++i) {
        int n = n0 + ty * 8 + i;
        if (n >= nNodes) continue;
        float4 o0, o1;
        o0.x = fmaxf(acc[i][0] + b0.x, 0.f);
        o0.y = fmaxf(acc[i][1] + b0.y, 0.f);
        o0.z = fmaxf(acc[i][2] + b0.z, 0.f);
        o0.w = fmaxf(acc[i][3] + b0.w, 0.f);
        o1.x = fmaxf(acc[i][4] + b1v.x, 0.f);
        o1.y = fmaxf(acc[i][5] + b1v.y, 0.f);
        o1.z = fmaxf(acc[i][6] + b1v.z, 0.f);
        o1.w = fmaxf(acc[i][7] + b1v.w, 0.f);
        *(float4*)(out + (size_t)n * HD + tx * 8) = o0;
        *(float4*)(out + (size_t)n * HD + tx * 8 + 4) = o1;
    }
}

// ---------------------------------------------------------------------------
// Pooling: pooled[g][coloff + j] += sum over nodes of graph g of h[n][j]
// ---------------------------------------------------------------------------
__global__ __launch_bounds__(128) void pool_k(const float* __restrict__ h,
                                              const int* __restrict__ gstart,
                                              float* __restrict__ pooled, int coloff) {
    int g = blockIdx.x, part = blockIdx.y, t = threadIdx.x;
    int lo = gstart[g], hi = gstart[g + 1];
    int cnt = hi - lo;
    if (cnt <= 0) return;
    int chunk = (cnt + 7) >> 3;
    int s = lo + part * chunk;
    int e = s + chunk; if (e > hi) e = hi;
    float acc = 0.f;
    for (int n = s; n < e; ++n) acc += h[(size_t)n * HD + t];
    if (s < e) atomicAdd(&pooled[g * 384 + coloff + t], acc);
}

// ---------------------------------------------------------------------------
// Classifier: z = relu(bn(pooled @ W1 + b1)); out = z @ W2 + b2
// ---------------------------------------------------------------------------
__global__ __launch_bounds__(256) void cls_k(const float* __restrict__ pooled,
                                             const float* __restrict__ W1,  // 384x256
                                             const float* __restrict__ b1,
                                             const float* __restrict__ gamma,
                                             const float* __restrict__ beta,
                                             const float* __restrict__ mean,
                                             const float* __restrict__ var,
                                             const float* __restrict__ W2,  // 256x4
                                             const float* __restrict__ b2,
                                             float* __restrict__ out) {
    __shared__ float pg[384];
    __shared__ float z[256];
    int g = blockIdx.x, j = threadIdx.x;
    pg[j] = pooled[g * 384 + j];
    if (j < 128) pg[256 + j] = pooled[g * 384 + 256 + j];
    __syncthreads();
    float acc = b1[j];
    for (int k = 0; k < 384; ++k) acc += pg[k] * W1[k * 256 + j];
    acc = (acc - mean[j]) * rsqrtf(var[j] + 1e-5f) * gamma[j] + beta[j];
    z[j] = fmaxf(acc, 0.f);
    __syncthreads();
    if (j < 4) {
        float o = b2[j];
        for (int k = 0; k < 256; ++k) o += z[k] * W2[k * 4 + j];
        out[g * 4 + j] = o;
    }
}

// ---------------------------------------------------------------------------
extern "C" void kernel_launch(void* const* d_in, const int* in_sizes, int n_in,
                              void* d_out, int out_size, void* d_ws, size_t ws_size,
                              hipStream_t stream) {
    const int N = NNODES, E = NEDGES;
    const float* x     = (const float*)d_in[0];
    const int*   ei    = (const int*)d_in[1];
    const int*   batch = (const int*)d_in[2];
    const float* l1W1 = (const float*)d_in[3];
    const float* l1b1 = (const float*)d_in[4];
    const float* l1W2 = (const float*)d_in[5];
    const float* l1b2 = (const float*)d_in[6];
    const float* l2W1 = (const float*)d_in[7];
    const float* l2b1 = (const float*)d_in[8];
    const float* l2W2 = (const float*)d_in[9];
    const float* l2b2 = (const float*)d_in[10];
    const float* l3W1 = (const float*)d_in[11];
    const float* l3b1 = (const float*)d_in[12];
    const float* l3W2 = (const float*)d_in[13];
    const float* l3b2 = (const float*)d_in[14];
    const float* cW1  = (const float*)d_in[15];
    const float* cb1  = (const float*)d_in[16];
    const float* bnG  = (const float*)d_in[17];
    const float* bnB  = (const float*)d_in[18];
    const float* bnM  = (const float*)d_in[19];
    const float* bnV  = (const float*)d_in[20];
    const float* cW2  = (const float*)d_in[21];
    const float* cb2  = (const float*)d_in[22];

    const int* src = ei;
    const int* dst = ei + E;

    // workspace layout (floats)
    float* ws   = (float*)d_ws;
    float* tmp  = ws;                         // N*128
    float* h1   = tmp + (size_t)N * HD;       // N*128
    float* h2   = h1 + (size_t)N * HD;        // N*128
    float* h3   = h2 + (size_t)N * HD;        // N*128
    float* pooled = h3 + (size_t)N * HD;      // 64*384
    int* count    = (int*)(pooled + 64 * 384);  // N
    int* row_tmp  = count + N;                  // N
    int* blocksum = row_tmp + N;                // 256
    int* blockoff = blocksum + 256;             // 256
    int* row_start = blockoff + 256;            // N+1
    int* cur       = row_start + N + 1;         // N
    int* nbr       = cur + N;                   // E
    int* gstart    = nbr + E;                   // 65

    hipMemsetAsync(count, 0, (size_t)N * 4, stream);
    hipMemsetAsync(pooled, 0, (size_t)64 * 384 * 4, stream);

    const int nB = (N + 255) / 256;      // 196 blocks of 256
    hist_k<<<(E + 255) / 256, 256, 0, stream>>>(dst, count, E);
    scan1_k<<<nB, 256, 0, stream>>>(count, row_tmp, blocksum, N);
    scan2_k<<<1, 256, 0, stream>>>(blocksum, blockoff, nB);
    scan3_k<<<nB, 256, 0, stream>>>(count, row_tmp, blockoff, row_start, cur, N, E);
    scatter_k<<<(E + 255) / 256, 256, 0, stream>>>(src, dst, cur, nbr, E);
    gstart_k<<<1, 128, 0, stream>>>(batch, gstart, N);

    const int mb = (N + 127) / 128;          // 391 tiles
    const int ab = (N * 64 + 255) / 256;     // 12500 blocks (1 wave per node)
    // layer 1
    lin8_k<<<mb, 256, 0, stream>>>(x, row_start, nbr, l1W1, l1b1, tmp, N);
    mm128_k<<<mb, 256, 0, stream>>>(tmp, l1W2, l1b2, h1, N);
    pool_k<<<dim3(NGRAPH, 8), 128, 0, stream>>>(h1, gstart, pooled, 0);
    // layer 2: agg -> mm (in-place) -> mm
    agg128_k<<<ab, 256, 0, stream>>>(h1, row_start, nbr, tmp, N);
    mm128_k<<<mb, 256, 0, stream>>>(tmp, l2W1, l2b1, tmp, N);
    mm128_k<<<mb, 256, 0, stream>>>(tmp, l2W2, l2b2, h2, N);
    pool_k<<<dim3(NGRAPH, 8), 128, 0, stream>>>(h2, gstart, pooled, 128);
    // layer 3
    agg128_k<<<ab, 256, 0, stream>>>(h2, row_start, nbr, tmp, N);
    mm128_k<<<mb, 256, 0, stream>>>(tmp, l3W1, l3b1, tmp, N);
    mm128_k<<<mb, 256, 0, stream>>>(tmp, l3W2, l3b2, h3, N);
    pool_k<<<dim3(NGRAPH, 8), 128, 0, stream>>>(h3, gstart, pooled, 256);
    // classifier
    cls_k<<<NGRAPH, 256, 0, stream>>>(pooled, cW1, cb1, bnG, bnB, bnM, bnV, cW2, cb2,
                                      (float*)d_out);
}

// Round 3
// 304.724 us; speedup vs baseline: 2.1429x; 1.5384x over previous
//
#include <hip/hip_runtime.h>
#include <hip/hip_bf16.h>

#define NNODES 50000
#define NEDGES 640000
#define NGRAPH 64
#define HD     128

typedef __attribute__((ext_vector_type(8))) short short8;
typedef __attribute__((ext_vector_type(4))) float f32x4;

__device__ __forceinline__ float uf(uint u) { return __uint_as_float(u); }
// fp32 -> bf16 round-to-nearest-even
__device__ __forceinline__ ushort f2b(float f) {
    uint u = __float_as_uint(f);
    return (ushort)((u + 0x7fffu + ((u >> 16) & 1u)) >> 16);
}

// ---------------------------------------------------------------------------
// CSR build: histogram -> 2-level exclusive scan -> scatter
// ---------------------------------------------------------------------------
__global__ __launch_bounds__(256) void hist_k(const int* __restrict__ dst,
                                              int* __restrict__ count, int E) {
    int e = blockIdx.x * 256 + threadIdx.x;
    if (e < E) atomicAdd(&count[dst[e]], 1);
}

__global__ __launch_bounds__(256) void scan1_k(const int* __restrict__ count,
                                               int* __restrict__ row_tmp,
                                               int* __restrict__ blocksum, int N) {
    __shared__ int s[256];
    int t = threadIdx.x;
    int i = blockIdx.x * 256 + t;
    int v = (i < N) ? count[i] : 0;
    s[t] = v;
    __syncthreads();
    for (int off = 1; off < 256; off <<= 1) {
        int nv = s[t];
        if (t >= off) nv += s[t - off];
        __syncthreads();
        s[t] = nv;
        __syncthreads();
    }
    if (i < N) row_tmp[i] = s[t];
    if (t == 255) blocksum[blockIdx.x] = s[255];
}

__global__ __launch_bounds__(256) void scan2_k(const int* __restrict__ blocksum,
                                               int* __restrict__ blockoff, int nB) {
    __shared__ int s[256];
    int t = threadIdx.x;
    int v = (t < nB) ? blocksum[t] : 0;
    s[t] = v;
    __syncthreads();
    for (int off = 1; off < 256; off <<= 1) {
        int nv = s[t];
        if (t >= off) nv += s[t - off];
        __syncthreads();
        s[t] = nv;
        __syncthreads();
    }
    if (t < nB) blockoff[t] = s[t] - v;
}

__global__ __launch_bounds__(256) void scan3_k(const int* __restrict__ count,
                                               const int* __restrict__ row_tmp,
                                               const int* __restrict__ blockoff,
                                               int* __restrict__ row_start,
                                               int* __restrict__ cur, int N, int E) {
    int i = blockIdx.x * 256 + threadIdx.x;
    if (i < N) {
        int excl = row_tmp[i] - count[i] + blockoff[i >> 8];
        row_start[i] = excl;
        cur[i] = excl;
    }
    if (i == N) row_start[N] = E;
}

__global__ __launch_bounds__(256) void scatter_k(const int* __restrict__ src,
                                                 const int* __restrict__ dst,
                                                 int* __restrict__ cur,
                                                 int* __restrict__ nbr, int E) {
    int e = blockIdx.x * 256 + threadIdx.x;
    if (e < E) {
        int d = dst[e];
        int pos = atomicAdd(&cur[d], 1);
        nbr[pos] = src[e];
    }
}

__global__ void gstart_k(const int* __restrict__ batch, int* __restrict__ gstart, int N) {
    int g = blockIdx.x * blockDim.x + threadIdx.x;
    if (g <= NGRAPH) {
        int lo = 0, hi = N;
        while (lo < hi) {
            int mid = (lo + hi) >> 1;
            if (batch[mid] < g) lo = mid + 1; else hi = mid;
        }
        gstart[g] = lo;
    }
}

// ---------------------------------------------------------------------------
// Pack fp32 128x128 weights into bf16 MFMA B-fragment order:
// Wp[((nt*4 + kt)*64 + lane)*8 + j] = bf16(W[kt*32 + (lane>>4)*8 + j][nt*16 + (lane&15)])
// grid: dim3(8, 5) x 256  (blockIdx.y selects which weight)
// ---------------------------------------------------------------------------
__global__ __launch_bounds__(256) void wpack_k(const float* __restrict__ W0,
                                               const float* __restrict__ W1,
                                               const float* __restrict__ W2,
                                               const float* __restrict__ W3,
                                               const float* __restrict__ W4,
                                               ushort* __restrict__ Wp) {
    int which = blockIdx.y;
    const float* W = (which == 0) ? W0 : (which == 1) ? W1 : (which == 2) ? W2
                   : (which == 3) ? W3 : W4;
    ushort* dst = Wp + (size_t)which * 16384;
    int idx = blockIdx.x * 256 + threadIdx.x;   // 0..2047
    int l  = idx & 63;
    int kt = (idx >> 6) & 3;
    int nt = idx >> 8;
    int krow = kt * 32 + (l >> 4) * 8;
    int col  = nt * 16 + (l & 15);
    short8 v;
#pragma unroll
    for (int j = 0; j < 8; ++j) v[j] = (short)f2b(W[(size_t)(krow + j) * HD + col]);
    *(short8*)(dst + ((size_t)(nt * 4 + kt) * 64 + l) * 8) = v;
}

// ---------------------------------------------------------------------------
// bf16 aggregation: out[n] = h[n] + sum_{s in nbr(n)} h[s]   (fp32 accumulate)
// 2 nodes per wave: lanes 0-31 node A, 32-63 node B; lane loads uint2 (4 bf16).
// ---------------------------------------------------------------------------
__global__ __launch_bounds__(256) void aggb_k(const ushort* __restrict__ h,
                                              const int* __restrict__ row_start,
                                              const int* __restrict__ nbr,
                                              ushort* __restrict__ out, int nNodes) {
    int gw   = (blockIdx.x * 256 + threadIdx.x) >> 6;
    int lane = threadIdx.x & 63;
    int node = gw * 2 + (lane >> 5);
    int sub  = lane & 31;                       // uint2 slot within the 256B row
    if (node >= nNodes) return;
    const uint2* hp = (const uint2*)h;
    uint2 u = hp[(size_t)node * 32 + sub];
    float f0 = uf(u.x << 16), f1 = uf(u.x & 0xffff0000u);
    float f2v = uf(u.y << 16), f3 = uf(u.y & 0xffff0000u);
    int rs = row_start[node], re = row_start[node + 1];
    int p = rs;
#define ACC4(vv) { f0 += uf(vv.x << 16); f1 += uf(vv.x & 0xffff0000u); \
                   f2v += uf(vv.y << 16); f3 += uf(vv.y & 0xffff0000u); }
    for (; p + 4 <= re; p += 4) {
        int s0 = nbr[p], s1 = nbr[p + 1], s2 = nbr[p + 2], s3 = nbr[p + 3];
        uint2 v0 = hp[(size_t)s0 * 32 + sub];
        uint2 v1 = hp[(size_t)s1 * 32 + sub];
        uint2 v2 = hp[(size_t)s2 * 32 + sub];
        uint2 v3 = hp[(size_t)s3 * 32 + sub];
        ACC4(v0) ACC4(v1) ACC4(v2) ACC4(v3)
    }
    for (; p < re; ++p) {
        int s = nbr[p];
        uint2 v = hp[(size_t)s * 32 + sub];
        ACC4(v)
    }
#undef ACC4
    uint2 o;
    o.x = (uint)f2b(f0) | ((uint)f2b(f1) << 16);
    o.y = (uint)f2b(f2v) | ((uint)f2b(f3) << 16);
    ((uint2*)out)[(size_t)node * 32 + sub] = o;
}

// ---------------------------------------------------------------------------
// Layer 1: t = relu((x + agg(x)) @ W1 + b1), x: N x 8 fp32, out bf16
// ---------------------------------------------------------------------------
__global__ __launch_bounds__(256) void lin8_k(const float* __restrict__ x,
                                              const int* __restrict__ row_start,
                                              const int* __restrict__ nbr,
                                              const float* __restrict__ W,   // 8 x 128
                                              const float* __restrict__ bias,
                                              ushort* __restrict__ out, int nNodes) {
    __shared__ float hin[128][8];
    int t = threadIdx.x;
    int n0 = blockIdx.x * 128;
    {
        int r = t >> 1;
        int half = t & 1;
        int n = n0 + r;
        float4 v = make_float4(0.f, 0.f, 0.f, 0.f);
        if (n < nNodes) {
            v = *(const float4*)(x + (size_t)n * 8 + half * 4);
            int rs = row_start[n], re = row_start[n + 1];
            int p = rs;
            for (; p + 4 <= re; p += 4) {
                int s0 = nbr[p], s1 = nbr[p + 1], s2 = nbr[p + 2], s3 = nbr[p + 3];
                float4 u0 = *(const float4*)(x + (size_t)s0 * 8 + half * 4);
                float4 u1 = *(const float4*)(x + (size_t)s1 * 8 + half * 4);
                float4 u2 = *(const float4*)(x + (size_t)s2 * 8 + half * 4);
                float4 u3 = *(const float4*)(x + (size_t)s3 * 8 + half * 4);
                v.x += u0.x + u1.x + u2.x + u3.x;
                v.y += u0.y + u1.y + u2.y + u3.y;
                v.z += u0.z + u1.z + u2.z + u3.z;
                v.w += u0.w + u1.w + u2.w + u3.w;
            }
            for (; p < re; ++p) {
                int s = nbr[p];
                float4 u = *(const float4*)(x + (size_t)s * 8 + half * 4);
                v.x += u.x; v.y += u.y; v.z += u.z; v.w += u.w;
            }
        }
        *(float4*)(&hin[r][half * 4]) = v;
    }
    __syncthreads();
    int tx = t & 15, ty = t >> 4;
    float w[8][8];
#pragma unroll
    for (int k = 0; k < 8; ++k) {
        float4 w0 = *(const float4*)(W + k * HD + tx * 8);
        float4 w1 = *(const float4*)(W + k * HD + tx * 8 + 4);
        w[k][0] = w0.x; w[k][1] = w0.y; w[k][2] = w0.z; w[k][3] = w0.w;
        w[k][4] = w1.x; w[k][5] = w1.y; w[k][6] = w1.z; w[k][7] = w1.w;
    }
    float4 b0 = *(const float4*)(bias + tx * 8);
    float4 b1v = *(const float4*)(bias + tx * 8 + 4);
    float bb[8] = {b0.x, b0.y, b0.z, b0.w, b1v.x, b1v.y, b1v.z, b1v.w};
#pragma unroll
    for (int i = 0; i < 8; ++i) {
        int r = ty * 8 + i;
        int n = n0 + r;
        if (n >= nNodes) continue;
        float a[8];
        float4 a0 = *(const float4*)(&hin[r][0]);
        float4 a1 = *(const float4*)(&hin[r][4]);
        a[0] = a0.x; a[1] = a0.y; a[2] = a0.z; a[3] = a0.w;
        a[4] = a1.x; a[5] = a1.y; a[6] = a1.z; a[7] = a1.w;
        short8 ov;
#pragma unroll
        for (int jj = 0; jj < 8; ++jj) {
            float acc = bb[jj];
#pragma unroll
            for (int k = 0; k < 8; ++k) acc += a[k] * w[k][jj];
            ov[jj] = (short)f2b(fmaxf(acc, 0.f));
        }
        *(short8*)(out + (size_t)n * HD + tx * 8) = ov;
    }
}

// ---------------------------------------------------------------------------
// 128x128 bf16 MFMA GEMM step (within fused kernel):
// D_lds = bf16(relu(A_lds @ Wp + bias)), A/D in XOR-swizzled LDS tiles.
// 4 waves; wave w computes rows [w*32, w*32+32) x 128 cols.
// ---------------------------------------------------------------------------
__device__ __forceinline__ void gemm128(const ushort* __restrict__ A,
                                        const short8* __restrict__ Wp,
                                        const float* __restrict__ bias,
                                        ushort* __restrict__ D, int tid) {
    const int l = tid & 63, w = tid >> 6;
    const int lr = l & 15, lg = l >> 4;
    const int wbase = w * 32;
    const int sw = lr & 7;                 // row&7 for both row-frags (16 apart)
    f32x4 acc[2][8];
    const f32x4 z4 = {0.f, 0.f, 0.f, 0.f};
#pragma unroll
    for (int m = 0; m < 2; ++m)
#pragma unroll
        for (int n = 0; n < 8; ++n) acc[m][n] = z4;
#pragma unroll
    for (int kt = 0; kt < 4; ++kt) {
        const int pch = ((kt * 4 + lg) ^ sw) * 8;
        short8 a0 = *(const short8*)(A + (wbase + lr) * 128 + pch);
        short8 a1 = *(const short8*)(A + (wbase + 16 + lr) * 128 + pch);
#pragma unroll
        for (int n = 0; n < 8; ++n) {
            short8 b = Wp[(n * 4 + kt) * 64 + l];
            acc[0][n] = __builtin_amdgcn_mfma_f32_16x16x32_bf16(a0, b, acc[0][n], 0, 0, 0);
            acc[1][n] = __builtin_amdgcn_mfma_f32_16x16x32_bf16(a1, b, acc[1][n], 0, 0, 0);
        }
    }
    // epilogue: bias + relu + bf16, scatter into swizzled LDS tile
#pragma unroll
    for (int n = 0; n < 8; ++n) {
        const int col = n * 16 + lr;
        const float bb = bias[col];
        const int cch = col >> 3, cof = col & 7;
#pragma unroll
        for (int m = 0; m < 2; ++m) {
#pragma unroll
            for (int r = 0; r < 4; ++r) {
                int row = wbase + m * 16 + lg * 4 + r;
                float t = fmaxf(acc[m][n][r] + bb, 0.f);
                D[row * 128 + ((cch ^ (row & 7)) * 8) + cof] = f2b(t);
            }
        }
    }
}

// Fused per-layer MLP: NG==1: out = relu(A@W1+b1); NG==2: out = relu(relu(A@W1+b1)@W2+b2)
template <int NG>
__global__ __launch_bounds__(256) void fmm_k(const ushort* __restrict__ Ain,
                                             const short8* __restrict__ Wp1,
                                             const float* __restrict__ b1,
                                             const short8* __restrict__ Wp2,
                                             const float* __restrict__ b2,
                                             ushort* __restrict__ out, int nNodes) {
    __shared__ __align__(16) ushort At[128 * 128];
    __shared__ __align__(16) ushort Tt[128 * 128];
    const int tid = threadIdx.x;
    const int n0 = blockIdx.x * 128;
    // stage A (bf16, XOR-swizzled 16B chunks)
#pragma unroll
    for (int i = 0; i < 8; ++i) {
        int idx = i * 256 + tid;
        int row = idx >> 4, ch = idx & 15;
        short8 v = {0, 0, 0, 0, 0, 0, 0, 0};
        int n = n0 + row;
        if (n < nNodes) v = *(const short8*)(Ain + (size_t)n * HD + ch * 8);
        *(short8*)(At + row * 128 + ((ch ^ (row & 7)) * 8)) = v;
    }
    __syncthreads();
    gemm128(At, Wp1, b1, Tt, tid);
    __syncthreads();
    const ushort* S = Tt;
    if constexpr (NG == 2) {
        gemm128(Tt, Wp2, b2, At, tid);
        __syncthreads();
        S = At;
    }
    // coalesced store-out
#pragma unroll
    for (int i = 0; i < 8; ++i) {
        int idx = i * 256 + tid;
        int row = idx >> 4, ch = idx & 15;
        int n = n0 + row;
        if (n < nNodes) {
            short8 v = *(const short8*)(S + row * 128 + ((ch ^ (row & 7)) * 8));
            *(short8*)(out + (size_t)n * HD + ch * 8) = v;
        }
    }
}

// ---------------------------------------------------------------------------
// Pooling over bf16 h (fp32 accumulate)
// ---------------------------------------------------------------------------
__global__ __launch_bounds__(128) void pool_k(const ushort* __restrict__ h,
                                              const int* __restrict__ gstart,
                                              float* __restrict__ pooled, int coloff) {
    int g = blockIdx.x, part = blockIdx.y, t = threadIdx.x;
    int lo = gstart[g], hi = gstart[g + 1];
    int cnt = hi - lo;
    if (cnt <= 0) return;
    int chunk = (cnt + 7) >> 3;
    int s = lo + part * chunk;
    int e = s + chunk; if (e > hi) e = hi;
    float acc = 0.f;
    for (int n = s; n < e; ++n) acc += uf((uint)h[(size_t)n * HD + t] << 16);
    if (s < e) atomicAdd(&pooled[g * 384 + coloff + t], acc);
}

// ---------------------------------------------------------------------------
// Classifier (all fp32)
// ---------------------------------------------------------------------------
__global__ __launch_bounds__(256) void cls_k(const float* __restrict__ pooled,
                                             const float* __restrict__ W1,  // 384x256
                                             const float* __restrict__ b1,
                                             const float* __restrict__ gamma,
                                             const float* __restrict__ beta,
                                             const float* __restrict__ mean,
                                             const float* __restrict__ var,
                                             const float* __restrict__ W2,  // 256x4
                                             const float* __restrict__ b2,
                                             float* __restrict__ out) {
    __shared__ float pg[384];
    __shared__ float z[256];
    int g = blockIdx.x, j = threadIdx.x;
    pg[j] = pooled[g * 384 + j];
    if (j < 128) pg[256 + j] = pooled[g * 384 + 256 + j];
    __syncthreads();
    float acc = b1[j];
    for (int k = 0; k < 384; ++k) acc += pg[k] * W1[k * 256 + j];
    acc = (acc - mean[j]) * rsqrtf(var[j] + 1e-5f) * gamma[j] + beta[j];
    z[j] = fmaxf(acc, 0.f);
    __syncthreads();
    if (j < 4) {
        float o = b2[j];
        for (int k = 0; k < 256; ++k) o += z[k] * W2[k * 4 + j];
        out[g * 4 + j] = o;
    }
}

// ---------------------------------------------------------------------------
extern "C" void kernel_launch(void* const* d_in, const int* in_sizes, int n_in,
                              void* d_out, int out_size, void* d_ws, size_t ws_size,
                              hipStream_t stream) {
    const int N = NNODES, E = NEDGES;
    const float* x     = (const float*)d_in[0];
    const int*   ei    = (const int*)d_in[1];
    const int*   batch = (const int*)d_in[2];
    const float* l1W1 = (const float*)d_in[3];
    const float* l1b1 = (const float*)d_in[4];
    const float* l1W2 = (const float*)d_in[5];
    const float* l1b2 = (const float*)d_in[6];
    const float* l2W1 = (const float*)d_in[7];
    const float* l2b1 = (const float*)d_in[8];
    const float* l2W2 = (const float*)d_in[9];
    const float* l2b2 = (const float*)d_in[10];
    const float* l3W1 = (const float*)d_in[11];
    const float* l3b1 = (const float*)d_in[12];
    const float* l3W2 = (const float*)d_in[13];
    const float* l3b2 = (const float*)d_in[14];
    const float* cW1  = (const float*)d_in[15];
    const float* cb1  = (const float*)d_in[16];
    const float* bnG  = (const float*)d_in[17];
    const float* bnB  = (const float*)d_in[18];
    const float* bnM  = (const float*)d_in[19];
    const float* bnV  = (const float*)d_in[20];
    const float* cW2  = (const float*)d_in[21];
    const float* cb2  = (const float*)d_in[22];

    const int* src = ei;
    const int* dst = ei + E;

    // ---- workspace layout ----
    char* wsp = (char*)d_ws;
    ushort* tmpb = (ushort*)wsp;  wsp += (size_t)N * HD * 2;   // bf16 N x 128
    ushort* h1   = (ushort*)wsp;  wsp += (size_t)N * HD * 2;
    ushort* h2   = (ushort*)wsp;  wsp += (size_t)N * HD * 2;
    ushort* h3   = (ushort*)wsp;  wsp += (size_t)N * HD * 2;
    float* pooled = (float*)wsp;  wsp += (size_t)64 * 384 * 4;
    ushort* wp    = (ushort*)wsp; wsp += (size_t)5 * 16384 * 2;
    int* count    = (int*)wsp;    wsp += (size_t)N * 4;
    int* row_tmp  = (int*)wsp;    wsp += (size_t)N * 4;
    int* blocksum = (int*)wsp;    wsp += 256 * 4;
    int* blockoff = (int*)wsp;    wsp += 256 * 4;
    int* row_start = (int*)wsp;   wsp += (size_t)(N + 1) * 4;
    int* cur       = (int*)wsp;   wsp += (size_t)N * 4;
    int* nbr       = (int*)wsp;   wsp += (size_t)E * 4;
    int* gstart    = (int*)wsp;   wsp += 65 * 4;

    hipMemsetAsync(count, 0, (size_t)N * 4, stream);
    hipMemsetAsync(pooled, 0, (size_t)64 * 384 * 4, stream);

    const int nB = (N + 255) / 256;
    hist_k<<<(E + 255) / 256, 256, 0, stream>>>(dst, count, E);
    scan1_k<<<nB, 256, 0, stream>>>(count, row_tmp, blocksum, N);
    scan2_k<<<1, 256, 0, stream>>>(blocksum, blockoff, nB);
    scan3_k<<<nB, 256, 0, stream>>>(count, row_tmp, blockoff, row_start, cur, N, E);
    scatter_k<<<(E + 255) / 256, 256, 0, stream>>>(src, dst, cur, nbr, E);
    gstart_k<<<1, 128, 0, stream>>>(batch, gstart, N);
    wpack_k<<<dim3(8, 5), 256, 0, stream>>>(l1W2, l2W1, l2W2, l3W1, l3W2, wp);

    const short8* Wp0 = (const short8*)(wp);
    const short8* Wp1 = (const short8*)(wp + 16384);
    const short8* Wp2 = (const short8*)(wp + 2 * 16384);
    const short8* Wp3 = (const short8*)(wp + 3 * 16384);
    const short8* Wp4 = (const short8*)(wp + 4 * 16384);

    const int mb = (N + 127) / 128;              // 391 tiles
    const int ab = ((N + 1) / 2 * 64) / 256;     // 6250 blocks (2 nodes/wave)
    // layer 1
    lin8_k<<<mb, 256, 0, stream>>>(x, row_start, nbr, l1W1, l1b1, tmpb, N);
    fmm_k<1><<<mb, 256, 0, stream>>>(tmpb, Wp0, l1b2, nullptr, nullptr, h1, N);
    pool_k<<<dim3(NGRAPH, 8), 128, 0, stream>>>(h1, gstart, pooled, 0);
    // layer 2
    aggb_k<<<ab, 256, 0, stream>>>(h1, row_start, nbr, tmpb, N);
    fmm_k<2><<<mb, 256, 0, stream>>>(tmpb, Wp1, l2b1, Wp2, l2b2, h2, N);
    pool_k<<<dim3(NGRAPH, 8), 128, 0, stream>>>(h2, gstart, pooled, 128);
    // layer 3
    aggb_k<<<ab, 256, 0, stream>>>(h2, row_start, nbr, tmpb, N);
    fmm_k<2><<<mb, 256, 0, stream>>>(tmpb, Wp3, l3b1, Wp4, l3b2, h3, N);
    pool_k<<<dim3(NGRAPH, 8), 128, 0, stream>>>(h3, gstart, pooled, 256);
    // classifier
    cls_k<<<NGRAPH, 256, 0, stream>>>(pooled, cW1, cb1, bnG, bnB, bnM, bnV, cW2, cb2,
                                      (float*)d_out);
}

// Round 4
// 223.155 us; speedup vs baseline: 2.9262x; 1.3655x over previous
//
#include <hip/hip_runtime.h>
#include <hip/hip_bf16.h>

#define NNODES 50000
#define NEDGES 640000
#define NGRAPH 64
#define HD     128

typedef __attribute__((ext_vector_type(8))) short short8;
typedef __attribute__((ext_vector_type(4))) float f32x4;

__device__ __forceinline__ float uf(uint u) { return __uint_as_float(u); }
// fp32 -> bf16 round-to-nearest-even
__device__ __forceinline__ ushort f2b(float f) {
    uint u = __float_as_uint(f);
    return (ushort)((u + 0x7fffu + ((u >> 16) & 1u)) >> 16);
}

// ---------------------------------------------------------------------------
// init: zero count + pooled, compute gstart (binary search on sorted batch)
// ---------------------------------------------------------------------------
__global__ __launch_bounds__(256) void init_k(const int* __restrict__ batch,
                                              int* __restrict__ count,
                                              float* __restrict__ pooled,
                                              int* __restrict__ gstart) {
    int idx = blockIdx.x * 256 + threadIdx.x;
    if (idx < NNODES) count[idx] = 0;
    if (idx < NGRAPH * 384) pooled[idx] = 0.f;
    if (blockIdx.x == 255 && threadIdx.x <= NGRAPH) {
        int g = threadIdx.x;
        int lo = 0, hi = NNODES;
        while (lo < hi) {
            int mid = (lo + hi) >> 1;
            if (batch[mid] < g) lo = mid + 1; else hi = mid;
        }
        gstart[g] = lo;
    }
}

// ---------------------------------------------------------------------------
// CSR build: histogram -> block scan -> (re-scan blocksums + finalize) -> scatter
// ---------------------------------------------------------------------------
__global__ __launch_bounds__(256) void hist_k(const int* __restrict__ dst,
                                              int* __restrict__ count, int E) {
    int e = blockIdx.x * 256 + threadIdx.x;
    if (e < E) atomicAdd(&count[dst[e]], 1);
}

__global__ __launch_bounds__(256) void scan1_k(const int* __restrict__ count,
                                               int* __restrict__ row_tmp,
                                               int* __restrict__ blocksum, int N) {
    __shared__ int s[256];
    int t = threadIdx.x;
    int i = blockIdx.x * 256 + t;
    int v = (i < N) ? count[i] : 0;
    s[t] = v;
    __syncthreads();
    for (int off = 1; off < 256; off <<= 1) {
        int nv = s[t];
        if (t >= off) nv += s[t - off];
        __syncthreads();
        s[t] = nv;
        __syncthreads();
    }
    if (i < N) row_tmp[i] = s[t];          // inclusive within block
    if (t == 255) blocksum[blockIdx.x] = s[255];
}

// every block re-scans the (<=256) blocksums locally, then finalizes its rows
__global__ __launch_bounds__(256) void scan23_k(const int* __restrict__ count,
                                                const int* __restrict__ row_tmp,
                                                const int* __restrict__ blocksum,
                                                int nB,
                                                int* __restrict__ row_start,
                                                int* __restrict__ cur, int N, int E) {
    __shared__ int s[256];
    int t = threadIdx.x;
    s[t] = (t < nB) ? blocksum[t] : 0;
    __syncthreads();
    for (int off = 1; off < 256; off <<= 1) {
        int nv = s[t];
        if (t >= off) nv += s[t - off];
        __syncthreads();
        s[t] = nv;
        __syncthreads();
    }
    int bid = blockIdx.x;
    int boff = (bid == 0) ? 0 : s[bid - 1];
    int i = bid * 256 + t;
    if (i < N) {
        int excl = row_tmp[i] - count[i] + boff;
        row_start[i] = excl;
        cur[i] = excl;
    }
    if (i == N) row_start[N] = E;
}

__global__ __launch_bounds__(256) void scatter_k(const int* __restrict__ src,
                                                 const int* __restrict__ dst,
                                                 int* __restrict__ cur,
                                                 int* __restrict__ nbr, int E) {
    int e = blockIdx.x * 256 + threadIdx.x;
    if (e < E) {
        int d = dst[e];
        int pos = atomicAdd(&cur[d], 1);
        nbr[pos] = src[e];
    }
}

// ---------------------------------------------------------------------------
// Pack fp32 128x128 weights into bf16 MFMA B-fragment order
// ---------------------------------------------------------------------------
__global__ __launch_bounds__(256) void wpack_k(const float* __restrict__ W0,
                                               const float* __restrict__ W1,
                                               const float* __restrict__ W2,
                                               const float* __restrict__ W3,
                                               const float* __restrict__ W4,
                                               ushort* __restrict__ Wp) {
    int which = blockIdx.y;
    const float* W = (which == 0) ? W0 : (which == 1) ? W1 : (which == 2) ? W2
                   : (which == 3) ? W3 : W4;
    ushort* dst = Wp + (size_t)which * 16384;
    int idx = blockIdx.x * 256 + threadIdx.x;   // 0..2047
    int l  = idx & 63;
    int kt = (idx >> 6) & 3;
    int nt = idx >> 8;
    int krow = kt * 32 + (l >> 4) * 8;
    int col  = nt * 16 + (l & 15);
    short8 v;
#pragma unroll
    for (int j = 0; j < 8; ++j) v[j] = (short)f2b(W[(size_t)(krow + j) * HD + col]);
    *(short8*)(dst + ((size_t)(nt * 4 + kt) * 64 + l) * 8) = v;
}

// ---------------------------------------------------------------------------
// bf16 aggregation: out[n] = h[n] + sum_{s in nbr(n)} h[s]   (fp32 accumulate)
// 2 nodes per wave; zero LDS, low VGPR -> max occupancy.
// ---------------------------------------------------------------------------
__global__ __launch_bounds__(256) void aggb_k(const ushort* __restrict__ h,
                                              const int* __restrict__ row_start,
                                              const int* __restrict__ nbr,
                                              ushort* __restrict__ out, int nNodes) {
    int gw   = (blockIdx.x * 256 + threadIdx.x) >> 6;
    int lane = threadIdx.x & 63;
    int node = gw * 2 + (lane >> 5);
    int sub  = lane & 31;
    if (node >= nNodes) return;
    const uint2* hp = (const uint2*)h;
    uint2 u = hp[(size_t)node * 32 + sub];
    float f0 = uf(u.x << 16), f1 = uf(u.x & 0xffff0000u);
    float f2v = uf(u.y << 16), f3 = uf(u.y & 0xffff0000u);
    int rs = row_start[node], re = row_start[node + 1];
    int p = rs;
#define ACC4(vv) { f0 += uf(vv.x << 16); f1 += uf(vv.x & 0xffff0000u); \
                   f2v += uf(vv.y << 16); f3 += uf(vv.y & 0xffff0000u); }
    for (; p + 4 <= re; p += 4) {
        int s0 = nbr[p], s1 = nbr[p + 1], s2 = nbr[p + 2], s3 = nbr[p + 3];
        uint2 v0 = hp[(size_t)s0 * 32 + sub];
        uint2 v1 = hp[(size_t)s1 * 32 + sub];
        uint2 v2 = hp[(size_t)s2 * 32 + sub];
        uint2 v3 = hp[(size_t)s3 * 32 + sub];
        ACC4(v0) ACC4(v1) ACC4(v2) ACC4(v3)
    }
    for (; p < re; ++p) {
        int s = nbr[p];
        uint2 v = hp[(size_t)s * 32 + sub];
        ACC4(v)
    }
#undef ACC4
    uint2 o;
    o.x = (uint)f2b(f0) | ((uint)f2b(f1) << 16);
    o.y = (uint)f2b(f2v) | ((uint)f2b(f3) << 16);
    ((uint2*)out)[(size_t)node * 32 + sub] = o;
}

// ---------------------------------------------------------------------------
// 128x128 bf16 MFMA GEMM step on an LDS tile. In-place safe: wave w only
// reads/writes rows [32w, 32w+32). D = bf16(relu(A @ Wp + bias)).
// ---------------------------------------------------------------------------
__device__ __forceinline__ void gemm128(const ushort* __restrict__ A,
                                        const short8* __restrict__ Wp,
                                        const float* __restrict__ bias,
                                        ushort* __restrict__ D, int tid) {
    const int l = tid & 63, w = tid >> 6;
    const int lr = l & 15, lg = l >> 4;
    const int wbase = w * 32;
    const int sw = lr & 7;
    f32x4 acc[2][8];
    const f32x4 z4 = {0.f, 0.f, 0.f, 0.f};
#pragma unroll
    for (int m = 0; m < 2; ++m)
#pragma unroll
        for (int n = 0; n < 8; ++n) acc[m][n] = z4;
#pragma unroll
    for (int kt = 0; kt < 4; ++kt) {
        const int pch = ((kt * 4 + lg) ^ sw) * 8;
        short8 a0 = *(const short8*)(A + (wbase + lr) * 128 + pch);
        short8 a1 = *(const short8*)(A + (wbase + 16 + lr) * 128 + pch);
#pragma unroll
        for (int n = 0; n < 8; ++n) {
            short8 b = Wp[(n * 4 + kt) * 64 + l];
            acc[0][n] = __builtin_amdgcn_mfma_f32_16x16x32_bf16(a0, b, acc[0][n], 0, 0, 0);
            acc[1][n] = __builtin_amdgcn_mfma_f32_16x16x32_bf16(a1, b, acc[1][n], 0, 0, 0);
        }
    }
#pragma unroll
    for (int n = 0; n < 8; ++n) {
        const int col = n * 16 + lr;
        const float bb = bias[col];
        const int cch = col >> 3, cof = col & 7;
#pragma unroll
        for (int m = 0; m < 2; ++m) {
#pragma unroll
            for (int r = 0; r < 4; ++r) {
                int row = wbase + m * 16 + lg * 4 + r;
                float t = fmaxf(acc[m][n][r] + bb, 0.f);
                D[row * 128 + ((cch ^ (row & 7)) * 8) + cof] = f2b(t);
            }
        }
    }
}

// Segmented pool of the LDS tile into pooled[g*384 + coloff + col].
// batch sorted -> per-block runs; guard g>=0 skips tail-garbage rows.
__device__ __forceinline__ void pool_tile(const ushort* __restrict__ T,
                                          const int* __restrict__ batchl,
                                          float* __restrict__ pooled,
                                          int coloff, int tid) {
    int col = tid & 127, half = tid >> 7;
    int cch = col >> 3, cof = col & 7;
    float pacc = 0.f;
    int curg = -1;
    for (int r = half * 64; r < half * 64 + 64; ++r) {
        int g = batchl[r];
        if (g != curg) {
            if (curg >= 0) atomicAdd(&pooled[curg * 384 + coloff + col], pacc);
            curg = g;
            pacc = 0.f;
        }
        if (g >= 0) pacc += uf((uint)T[r * 128 + ((cch ^ (r & 7)) * 8) + cof] << 16);
    }
    if (curg >= 0) atomicAdd(&pooled[curg * 384 + coloff + col], pacc);
}

// ---------------------------------------------------------------------------
// Fused layer 1: h1 = relu(relu((x + agg(x)) @ W1 + b1) @ W2 + b2) + pool
// x: N x 8 fp32. LDS: hin 4KB + T 32KB + batchl.
// ---------------------------------------------------------------------------
__global__ __launch_bounds__(256) void fl1_k(const float* __restrict__ x,
                                             const int* __restrict__ batch,
                                             const int* __restrict__ row_start,
                                             const int* __restrict__ nbr,
                                             const float* __restrict__ W1, // 8x128
                                             const float* __restrict__ b1,
                                             const short8* __restrict__ Wp2,
                                             const float* __restrict__ b2,
                                             ushort* __restrict__ out,
                                             float* __restrict__ pooled, int nNodes) {
    __shared__ float hin[128][8];
    __shared__ __align__(16) ushort T[128 * 128];
    __shared__ int batchl[128];
    int t = threadIdx.x;
    int n0 = blockIdx.x * 128;
    if (t < 128) batchl[t] = (n0 + t < nNodes) ? batch[n0 + t] : -1;
    {   // gather-sum staging: 2 threads per row (fp32 half-rows)
        int r = t >> 1;
        int half = t & 1;
        int n = n0 + r;
        float4 v = make_float4(0.f, 0.f, 0.f, 0.f);
        if (n < nNodes) {
            v = *(const float4*)(x + (size_t)n * 8 + half * 4);
            int rs = row_start[n], re = row_start[n + 1];
            int p = rs;
            for (; p + 4 <= re; p += 4) {
                int s0 = nbr[p], s1 = nbr[p + 1], s2 = nbr[p + 2], s3 = nbr[p + 3];
                float4 u0 = *(const float4*)(x + (size_t)s0 * 8 + half * 4);
                float4 u1 = *(const float4*)(x + (size_t)s1 * 8 + half * 4);
                float4 u2 = *(const float4*)(x + (size_t)s2 * 8 + half * 4);
                float4 u3 = *(const float4*)(x + (size_t)s3 * 8 + half * 4);
                v.x += u0.x + u1.x + u2.x + u3.x;
                v.y += u0.y + u1.y + u2.y + u3.y;
                v.z += u0.z + u1.z + u2.z + u3.z;
                v.w += u0.w + u1.w + u2.w + u3.w;
            }
            for (; p < re; ++p) {
                int s = nbr[p];
                float4 u = *(const float4*)(x + (size_t)s * 8 + half * 4);
                v.x += u.x; v.y += u.y; v.z += u.z; v.w += u.w;
            }
        }
        *(float4*)(&hin[r][half * 4]) = v;
    }
    __syncthreads();
    // MLP1 (8->128), bf16 result into swizzled T
    int tx = t & 15, ty = t >> 4;
    float w[8][8];
#pragma unroll
    for (int k = 0; k < 8; ++k) {
        float4 w0 = *(const float4*)(W1 + k * HD + tx * 8);
        float4 w1 = *(const float4*)(W1 + k * HD + tx * 8 + 4);
        w[k][0] = w0.x; w[k][1] = w0.y; w[k][2] = w0.z; w[k][3] = w0.w;
        w[k][4] = w1.x; w[k][5] = w1.y; w[k][6] = w1.z; w[k][7] = w1.w;
    }
    float4 c0 = *(const float4*)(b1 + tx * 8);
    float4 c1 = *(const float4*)(b1 + tx * 8 + 4);
    float bb[8] = {c0.x, c0.y, c0.z, c0.w, c1.x, c1.y, c1.z, c1.w};
#pragma unroll
    for (int i = 0; i < 8; ++i) {
        int r = ty * 8 + i;
        float4 a0 = *(const float4*)(&hin[r][0]);
        float4 a1 = *(const float4*)(&hin[r][4]);
        float a[8] = {a0.x, a0.y, a0.z, a0.w, a1.x, a1.y, a1.z, a1.w};
        short8 ov;
#pragma unroll
        for (int jj = 0; jj < 8; ++jj) {
            float acc = bb[jj];
#pragma unroll
            for (int k = 0; k < 8; ++k) acc += a[k] * w[k][jj];
            ov[jj] = (short)f2b(fmaxf(acc, 0.f));
        }
        *(short8*)(T + r * 128 + ((tx ^ (r & 7)) * 8)) = ov;
    }
    __syncthreads();
    gemm128(T, Wp2, b2, T, t);     // in-place, wave-private rows
    __syncthreads();
    // store + fused pool
#pragma unroll
    for (int i = 0; i < 8; ++i) {
        int idx = i * 256 + t;
        int row = idx >> 4, ch = idx & 15;
        int n = n0 + row;
        if (n < nNodes) {
            short8 v = *(const short8*)(T + row * 128 + ((ch ^ (row & 7)) * 8));
            *(short8*)(out + (size_t)n * HD + ch * 8) = v;
        }
    }
    pool_tile(T, batchl, pooled, 0, t);
}

// ---------------------------------------------------------------------------
// Fused layer MLP (layers 2,3): out = relu(relu(A@W1+b1)@W2+b2) + pool.
// Single in-place 32KB tile -> 4 blocks/CU.
// ---------------------------------------------------------------------------
__global__ __launch_bounds__(256) void fmm_k(const ushort* __restrict__ Ain,
                                             const int* __restrict__ batch,
                                             const short8* __restrict__ Wp1,
                                             const float* __restrict__ b1,
                                             const short8* __restrict__ Wp2,
                                             const float* __restrict__ b2,
                                             ushort* __restrict__ out,
                                             float* __restrict__ pooled,
                                             int coloff, int nNodes) {
    __shared__ __align__(16) ushort T[128 * 128];
    __shared__ int batchl[128];
    const int t = threadIdx.x;
    const int n0 = blockIdx.x * 128;
    if (t < 128) batchl[t] = (n0 + t < nNodes) ? batch[n0 + t] : -1;
#pragma unroll
    for (int i = 0; i < 8; ++i) {
        int idx = i * 256 + t;
        int row = idx >> 4, ch = idx & 15;
        short8 v = {0, 0, 0, 0, 0, 0, 0, 0};
        int n = n0 + row;
        if (n < nNodes) v = *(const short8*)(Ain + (size_t)n * HD + ch * 8);
        *(short8*)(T + row * 128 + ((ch ^ (row & 7)) * 8)) = v;
    }
    __syncthreads();
    gemm128(T, Wp1, b1, T, t);
    __syncthreads();
    gemm128(T, Wp2, b2, T, t);
    __syncthreads();
#pragma unroll
    for (int i = 0; i < 8; ++i) {
        int idx = i * 256 + t;
        int row = idx >> 4, ch = idx & 15;
        int n = n0 + row;
        if (n < nNodes) {
            short8 v = *(const short8*)(T + row * 128 + ((ch ^ (row & 7)) * 8));
            *(short8*)(out + (size_t)n * HD + ch * 8) = v;
        }
    }
    pool_tile(T, batchl, pooled, coloff, t);
}

// ---------------------------------------------------------------------------
// Classifier (all fp32)
// ---------------------------------------------------------------------------
__global__ __launch_bounds__(256) void cls_k(const float* __restrict__ pooled,
                                             const float* __restrict__ W1,  // 384x256
                                             const float* __restrict__ b1,
                                             const float* __restrict__ gamma,
                                             const float* __restrict__ beta,
                                             const float* __restrict__ mean,
                                             const float* __restrict__ var,
                                             const float* __restrict__ W2,  // 256x4
                                             const float* __restrict__ b2,
                                             float* __restrict__ out) {
    __shared__ float pg[384];
    __shared__ float z[256];
    int g = blockIdx.x, j = threadIdx.x;
    pg[j] = pooled[g * 384 + j];
    if (j < 128) pg[256 + j] = pooled[g * 384 + 256 + j];
    __syncthreads();
    float acc = b1[j];
    for (int k = 0; k < 384; ++k) acc += pg[k] * W1[k * 256 + j];
    acc = (acc - mean[j]) * rsqrtf(var[j] + 1e-5f) * gamma[j] + beta[j];
    z[j] = fmaxf(acc, 0.f);
    __syncthreads();
    if (j < 4) {
        float o = b2[j];
        for (int k = 0; k < 256; ++k) o += z[k] * W2[k * 4 + j];
        out[g * 4 + j] = o;
    }
}

// ---------------------------------------------------------------------------
extern "C" void kernel_launch(void* const* d_in, const int* in_sizes, int n_in,
                              void* d_out, int out_size, void* d_ws, size_t ws_size,
                              hipStream_t stream) {
    const int N = NNODES, E = NEDGES;
    const float* x     = (const float*)d_in[0];
    const int*   ei    = (const int*)d_in[1];
    const int*   batch = (const int*)d_in[2];
    const float* l1W1 = (const float*)d_in[3];
    const float* l1b1 = (const float*)d_in[4];
    const float* l1W2 = (const float*)d_in[5];
    const float* l1b2 = (const float*)d_in[6];
    const float* l2W1 = (const float*)d_in[7];
    const float* l2b1 = (const float*)d_in[8];
    const float* l2W2 = (const float*)d_in[9];
    const float* l2b2 = (const float*)d_in[10];
    const float* l3W1 = (const float*)d_in[11];
    const float* l3b1 = (const float*)d_in[12];
    const float* l3W2 = (const float*)d_in[13];
    const float* l3b2 = (const float*)d_in[14];
    const float* cW1  = (const float*)d_in[15];
    const float* cb1  = (const float*)d_in[16];
    const float* bnG  = (const float*)d_in[17];
    const float* bnB  = (const float*)d_in[18];
    const float* bnM  = (const float*)d_in[19];
    const float* bnV  = (const float*)d_in[20];
    const float* cW2  = (const float*)d_in[21];
    const float* cb2  = (const float*)d_in[22];

    const int* src = ei;
    const int* dst = ei + E;

    // ---- workspace layout ----
    char* wsp = (char*)d_ws;
    ushort* tmpb = (ushort*)wsp;  wsp += (size_t)N * HD * 2;
    ushort* h1   = (ushort*)wsp;  wsp += (size_t)N * HD * 2;
    ushort* h2   = (ushort*)wsp;  wsp += (size_t)N * HD * 2;
    ushort* h3   = (ushort*)wsp;  wsp += (size_t)N * HD * 2;
    float* pooled = (float*)wsp;  wsp += (size_t)64 * 384 * 4;
    ushort* wp    = (ushort*)wsp; wsp += (size_t)5 * 16384 * 2;
    int* count    = (int*)wsp;    wsp += (size_t)N * 4;
    int* row_tmp  = (int*)wsp;    wsp += (size_t)N * 4;
    int* blocksum = (int*)wsp;    wsp += 256 * 4;
    int* row_start = (int*)wsp;   wsp += (size_t)(N + 1) * 4;
    int* cur       = (int*)wsp;   wsp += (size_t)N * 4;
    int* nbr       = (int*)wsp;   wsp += (size_t)E * 4;
    int* gstart    = (int*)wsp;   wsp += 65 * 4;

    const int nB = (N + 255) / 256;              // 196
    init_k<<<256, 256, 0, stream>>>(batch, count, pooled, gstart);
    hist_k<<<(E + 255) / 256, 256, 0, stream>>>(dst, count, E);
    scan1_k<<<nB, 256, 0, stream>>>(count, row_tmp, blocksum, N);
    scan23_k<<<nB, 256, 0, stream>>>(count, row_tmp, blocksum, nB, row_start, cur, N, E);
    scatter_k<<<(E + 255) / 256, 256, 0, stream>>>(src, dst, cur, nbr, E);
    wpack_k<<<dim3(8, 5), 256, 0, stream>>>(l1W2, l2W1, l2W2, l3W1, l3W2, wp);

    const short8* Wp0 = (const short8*)(wp);
    const short8* Wp1 = (const short8*)(wp + 16384);
    const short8* Wp2 = (const short8*)(wp + 2 * 16384);
    const short8* Wp3 = (const short8*)(wp + 3 * 16384);
    const short8* Wp4 = (const short8*)(wp + 4 * 16384);

    const int mb = (N + 127) / 128;              // 391 tiles
    const int ab = ((N + 1) / 2 * 64) / 256;     // 6250 blocks
    // layer 1 (gather + MLP1 + GEMM2 + pool fused)
    fl1_k<<<mb, 256, 0, stream>>>(x, batch, row_start, nbr, l1W1, l1b1, Wp0, l1b2,
                                  h1, pooled, N);
    // layer 2
    aggb_k<<<ab, 256, 0, stream>>>(h1, row_start, nbr, tmpb, N);
    fmm_k<<<mb, 256, 0, stream>>>(tmpb, batch, Wp1, l2b1, Wp2, l2b2, h2, pooled, 128, N);
    // layer 3
    aggb_k<<<ab, 256, 0, stream>>>(h2, row_start, nbr, tmpb, N);
    fmm_k<<<mb, 256, 0, stream>>>(tmpb, batch, Wp3, l3b1, Wp4, l3b2, h3, pooled, 256, N);
    // classifier
    cls_k<<<NGRAPH, 256, 0, stream>>>(pooled, cW1, cb1, bnG, bnB, bnM, bnV, cW2, cb2,
                                      (float*)d_out);
}